// Round 1
// baseline (622.500 us; speedup 1.0000x reference)
//
#include <hip/hip_runtime.h>
#include <hip/hip_bf16.h>

#define HH 64
#define WW 64
#define CIN 128
#define COUT 256
#define KK 1152        // CIN*9
#define TP 32          // pixels per tile in deform kernel
#define CCHUNK 16      // channels per LDS chunk

// ---------------- kernel 0: transpose weights [Cout][1152] -> [1152][Cout] ----
__global__ void transpose_w(const float* __restrict__ wd, float* __restrict__ wt) {
    int ck = blockIdx.x;          // 0..1151
    int co = threadIdx.x;         // 0..255
    wt[ck * COUT + co] = wd[co * KK + ck];
}

// ---------------- kernel 1: offset conv (3x3, pad 1): x[8,128,64,64] -> off[8,18,64,64]
__global__ __launch_bounds__(256) void off_conv(const float* __restrict__ x,
                                                const float* __restrict__ w,
                                                const float* __restrict__ bias,
                                                float* __restrict__ off) {
    int b   = blockIdx.y;
    int pix = blockIdx.x * 256 + threadIdx.x;   // 0..4095
    int h = pix >> 6;
    int wcol = pix & 63;

    float acc[18];
#pragma unroll
    for (int o = 0; o < 18; o++) acc[o] = bias[o];

    const float* xb = x + (size_t)b * CIN * HH * WW;

    int hm1 = h - 1, hp1 = h + 1, wm1 = wcol - 1, wp1 = wcol + 1;
    bool vt = hm1 >= 0, vb = hp1 < HH, vl = wm1 >= 0, vr = wp1 < WW;
    int rT = max(hm1, 0) * WW, rM = h * WW, rB = min(hp1, HH - 1) * WW;
    int cL = max(wm1, 0), cM = wcol, cR = min(wp1, WW - 1);

    for (int c = 0; c < CIN; c++) {
        const float* xc = xb + c * (HH * WW);
        float xv0 = (vt && vl) ? xc[rT + cL] : 0.f;
        float xv1 = (vt      ) ? xc[rT + cM] : 0.f;
        float xv2 = (vt && vr) ? xc[rT + cR] : 0.f;
        float xv3 = (vl      ) ? xc[rM + cL] : 0.f;
        float xv4 =              xc[rM + cM];
        float xv5 = (vr      ) ? xc[rM + cR] : 0.f;
        float xv6 = (vb && vl) ? xc[rB + cL] : 0.f;
        float xv7 = (vb      ) ? xc[rB + cM] : 0.f;
        float xv8 = (vb && vr) ? xc[rB + cR] : 0.f;
#pragma unroll
        for (int o = 0; o < 18; o++) {
            const float* wo = w + o * KK + c * 9;
            acc[o] = fmaf(wo[0], xv0, acc[o]);
            acc[o] = fmaf(wo[1], xv1, acc[o]);
            acc[o] = fmaf(wo[2], xv2, acc[o]);
            acc[o] = fmaf(wo[3], xv3, acc[o]);
            acc[o] = fmaf(wo[4], xv4, acc[o]);
            acc[o] = fmaf(wo[5], xv5, acc[o]);
            acc[o] = fmaf(wo[6], xv6, acc[o]);
            acc[o] = fmaf(wo[7], xv7, acc[o]);
            acc[o] = fmaf(wo[8], xv8, acc[o]);
        }
    }
#pragma unroll
    for (int o = 0; o < 18; o++) {
        off[(((size_t)b * 18 + o) * HH + h) * WW + wcol] = acc[o];
    }
}

// ---------------- kernel 2: fused deformable sampling + contraction + bias + relu
// grid: 1024 blocks = B(8) * H(64) * (W/TP = 2), block = 256 threads (one Cout each)
__global__ __launch_bounds__(256, 2) void deform_gemm(const float* __restrict__ x,
                                                      const float* __restrict__ off,
                                                      const float* __restrict__ wt,   // [1152][256]
                                                      const float* __restrict__ bias,
                                                      float* __restrict__ out) {
    __shared__ __align__(16) float s_w[9][TP][4];   // 4 corner weights (validity-folded)
    __shared__ __align__(16) int   s_o[9][TP][4];   // 4 clamped corner flat offsets
    __shared__ float s_val[CCHUNK * 9][TP];

    int t  = threadIdx.x;
    int bi = blockIdx.x;
    int tile = bi & 1;
    int h    = (bi >> 1) & 63;
    int b    = bi >> 7;
    int w0   = tile * TP;

    // ---- precompute bilinear sampling params for 9 kernel points x TP pixels
    for (int j = t; j < 9 * TP; j += 256) {
        int k = j / TP, pix = j % TP;
        int wp = w0 + pix;
        float dy = off[(((size_t)b * 18 + 2 * k    ) * HH + h) * WW + wp];
        float dx = off[(((size_t)b * 18 + 2 * k + 1) * HH + h) * WW + wp];
        float py = (float)(h + k / 3 - 1) + dy;
        float px = (float)(wp + k % 3 - 1) + dx;
        float y0f = floorf(py), x0f = floorf(px);
        float ly = py - y0f, lx = px - x0f;
        int y0 = (int)y0f, x0 = (int)x0f;
        int y1 = y0 + 1, x1 = x0 + 1;
        bool vy0 = (y0 >= 0) && (y0 < HH);
        bool vy1 = (y1 >= 0) && (y1 < HH);
        bool vx0 = (x0 >= 0) && (x0 < WW);
        bool vx1 = (x1 >= 0) && (x1 < WW);
        int y0c = min(max(y0, 0), HH - 1), y1c = min(max(y1, 0), HH - 1);
        int x0c = min(max(x0, 0), WW - 1), x1c = min(max(x1, 0), WW - 1);
        s_o[k][pix][0] = y0c * WW + x0c;
        s_o[k][pix][1] = y0c * WW + x1c;
        s_o[k][pix][2] = y1c * WW + x0c;
        s_o[k][pix][3] = y1c * WW + x1c;
        s_w[k][pix][0] = (1.f - ly) * (1.f - lx) * ((vy0 && vx0) ? 1.f : 0.f);
        s_w[k][pix][1] = (1.f - ly) * lx         * ((vy0 && vx1) ? 1.f : 0.f);
        s_w[k][pix][2] = ly * (1.f - lx)         * ((vy1 && vx0) ? 1.f : 0.f);
        s_w[k][pix][3] = ly * lx                 * ((vy1 && vx1) ? 1.f : 0.f);
    }
    __syncthreads();

    float acc[TP];
#pragma unroll
    for (int p = 0; p < TP; p++) acc[p] = 0.f;

    const float* xb = x + (size_t)b * CIN * HH * WW;

    for (int c0 = 0; c0 < CIN; c0 += CCHUNK) {
        // ---- phase 1: build val chunk [CCHUNK*9][TP] in LDS
        for (int j = t; j < CCHUNK * 9 * TP; j += 256) {   // 18 iterations
            int pix = j & (TP - 1);
            int ckl = j / TP;                // 0..143
            int c = c0 + ckl / 9;
            int k = ckl % 9;
            const float* xc = xb + c * (HH * WW);
            int4   o4 = *(const int4*)(&s_o[k][pix][0]);
            float4 w4 = *(const float4*)(&s_w[k][pix][0]);
            float v = w4.x * xc[o4.x] + w4.y * xc[o4.y]
                    + w4.z * xc[o4.z] + w4.w * xc[o4.w];
            s_val[ckl][pix] = v;
        }
        __syncthreads();

        // ---- phase 2: each thread owns co = t, accumulates TP pixels
        const float* wtp = wt + (size_t)(c0 * 9) * COUT + t;
        for (int ckl = 0; ckl < CCHUNK * 9; ckl++) {
            float wv = wtp[(size_t)ckl * COUT];
#pragma unroll
            for (int p = 0; p < TP; p++) {
                acc[p] = fmaf(wv, s_val[ckl][p], acc[p]);
            }
        }
        __syncthreads();
    }

    float bb = bias[t];
    float* ob = out + (((size_t)b * COUT + t) * HH + h) * WW + w0;
#pragma unroll
    for (int p = 0; p < TP; p++) {
        ob[p] = fmaxf(acc[p] + bb, 0.f);
    }
}

extern "C" void kernel_launch(void* const* d_in, const int* in_sizes, int n_in,
                              void* d_out, int out_size, void* d_ws, size_t ws_size,
                              hipStream_t stream) {
    const float* x     = (const float*)d_in[0];
    const float* w_off = (const float*)d_in[1];
    const float* b_off = (const float*)d_in[2];
    const float* w_def = (const float*)d_in[3];
    const float* b_def = (const float*)d_in[4];
    float* out = (float*)d_out;

    // workspace layout: wk_t [1152*256] floats, then offsets [8*18*64*64] floats
    float* wk_t   = (float*)d_ws;
    float* offset = wk_t + (size_t)KK * COUT;

    transpose_w<<<KK, COUT, 0, stream>>>(w_def, wk_t);
    off_conv<<<dim3(16, 8), 256, 0, stream>>>(x, w_off, b_off, offset);
    deform_gemm<<<8 * 64 * (WW / TP), 256, 0, stream>>>(x, offset, wk_t, b_def, out);
}

// Round 2
// 270.877 us; speedup vs baseline: 2.2981x; 2.2981x over previous
//
#include <hip/hip_runtime.h>
#include <hip/hip_bf16.h>

#define HH 64
#define WW 64
#define CIN 128
#define COUT 256
#define KK 1152          // CIN*9
#define TP 32            // pixels per block tile
#define SVS (KK + 8)     // s_val row stride (bf16 elems): +8 pad = 4-bank lane shift

typedef short bf16x8 __attribute__((ext_vector_type(8)));
typedef float f32x4  __attribute__((ext_vector_type(4)));

__device__ inline short f2bf(float f) {
    union { float f; unsigned u; } v; v.f = f;
    unsigned r = v.u + 0x7FFFu + ((v.u >> 16) & 1u);   // RNE
    return (short)(r >> 16);
}

// ---- kernel 0: cast+permute weights: wb[co][ck'] = bf16(wd[co][c*9+k]), ck' = k*128+c
__global__ void cast_w(const float* __restrict__ wd, short* __restrict__ wb) {
    int co = blockIdx.x;                       // 0..255
    for (int ck = threadIdx.x; ck < KK; ck += 256) {
        int c = ck & 127, k = ck >> 7;
        wb[co * KK + ck] = f2bf(wd[co * KK + c * 9 + k]);
    }
}

// ---- kernel 1: init offset buffer with bias
__global__ void init_off(const float* __restrict__ bo, float* __restrict__ off) {
    int i = blockIdx.x * 256 + threadIdx.x;    // 589824 total
    off[i] = bo[(i >> 12) % 18];
}

// ---- kernel 2: offset conv, channel-split 4-way, atomic accumulate
__global__ __launch_bounds__(256) void off_conv_part(const float* __restrict__ x,
                                                     const float* __restrict__ w,
                                                     float* __restrict__ off) {
    int t = threadIdx.x;
    int b = blockIdx.y;
    int h = blockIdx.x * 4 + (t >> 6);
    int col = t & 63;
    int c0 = blockIdx.z * 32;

    float acc[18];
#pragma unroll
    for (int o = 0; o < 18; o++) acc[o] = 0.f;

    const float* xb = x + (size_t)b * CIN * HH * WW;
    int hm1 = h - 1, hp1 = h + 1, wm1 = col - 1, wp1 = col + 1;
    bool vt = hm1 >= 0, vb = hp1 < HH, vl = wm1 >= 0, vr = wp1 < WW;
    int rT = max(hm1, 0) * WW, rM = h * WW, rB = min(hp1, HH - 1) * WW;
    int cL = max(wm1, 0), cM = col, cR = min(wp1, WW - 1);

    for (int c = c0; c < c0 + 32; c++) {
        const float* xc = xb + c * (HH * WW);
        float xv0 = (vt && vl) ? xc[rT + cL] : 0.f;
        float xv1 = (vt      ) ? xc[rT + cM] : 0.f;
        float xv2 = (vt && vr) ? xc[rT + cR] : 0.f;
        float xv3 = (vl      ) ? xc[rM + cL] : 0.f;
        float xv4 =              xc[rM + cM];
        float xv5 = (vr      ) ? xc[rM + cR] : 0.f;
        float xv6 = (vb && vl) ? xc[rB + cL] : 0.f;
        float xv7 = (vb      ) ? xc[rB + cM] : 0.f;
        float xv8 = (vb && vr) ? xc[rB + cR] : 0.f;
#pragma unroll
        for (int o = 0; o < 18; o++) {
            const float* wo = w + o * KK + c * 9;
            acc[o] = fmaf(wo[0], xv0, acc[o]);
            acc[o] = fmaf(wo[1], xv1, acc[o]);
            acc[o] = fmaf(wo[2], xv2, acc[o]);
            acc[o] = fmaf(wo[3], xv3, acc[o]);
            acc[o] = fmaf(wo[4], xv4, acc[o]);
            acc[o] = fmaf(wo[5], xv5, acc[o]);
            acc[o] = fmaf(wo[6], xv6, acc[o]);
            acc[o] = fmaf(wo[7], xv7, acc[o]);
            acc[o] = fmaf(wo[8], xv8, acc[o]);
        }
    }
#pragma unroll
    for (int o = 0; o < 18; o++) {
        atomicAdd(&off[(((size_t)b * 18 + o) << 12) + h * WW + col], acc[o]);
    }
}

// ---- kernel 3: fused sampling (fp32) + bf16 MFMA contraction + bias + relu
// grid: 1024 = B(8) * H(64) * (W/TP=2); block 256 = 4 waves
__global__ __launch_bounds__(256, 2) void deform_mfma(const float* __restrict__ x,
                                                      const float* __restrict__ off,
                                                      const short* __restrict__ wb,  // [256][1152] bf16, k-major ck
                                                      const float* __restrict__ bias,
                                                      float* __restrict__ out) {
    __shared__ float  s_w[9][TP][4];          // 4 corner weights (validity folded)
    __shared__ ushort s_o[9][TP][4];          // 4 clamped corner flat offsets
    __shared__ short  s_val[TP][SVS];         // bf16 val, [pix][ck'] for B-frags

    int t  = threadIdx.x;
    int bi = blockIdx.x;
    int tile = bi & 1;
    int h    = (bi >> 1) & 63;
    int b    = bi >> 7;
    int w0   = tile * TP;

    // ---- sampling params: 9 kernel points x 32 pixels
    for (int j = t; j < 9 * TP; j += 256) {
        int k = j >> 5, pix = j & 31;
        int wp = w0 + pix;
        float dy = off[(((size_t)b * 18 + 2 * k    ) * HH + h) * WW + wp];
        float dx = off[(((size_t)b * 18 + 2 * k + 1) * HH + h) * WW + wp];
        float py = (float)(h + k / 3 - 1) + dy;
        float px = (float)(wp + k % 3 - 1) + dx;
        float y0f = floorf(py), x0f = floorf(px);
        float ly = py - y0f, lx = px - x0f;
        int y0 = (int)y0f, x0 = (int)x0f;
        int y1 = y0 + 1, x1 = x0 + 1;
        bool vy0 = (y0 >= 0) && (y0 < HH);
        bool vy1 = (y1 >= 0) && (y1 < HH);
        bool vx0 = (x0 >= 0) && (x0 < WW);
        bool vx1 = (x1 >= 0) && (x1 < WW);
        int y0c = min(max(y0, 0), HH - 1), y1c = min(max(y1, 0), HH - 1);
        int x0c = min(max(x0, 0), WW - 1), x1c = min(max(x1, 0), WW - 1);
        s_o[k][pix][0] = (ushort)(y0c * WW + x0c);
        s_o[k][pix][1] = (ushort)(y0c * WW + x1c);
        s_o[k][pix][2] = (ushort)(y1c * WW + x0c);
        s_o[k][pix][3] = (ushort)(y1c * WW + x1c);
        s_w[k][pix][0] = (1.f - ly) * (1.f - lx) * ((vy0 && vx0) ? 1.f : 0.f);
        s_w[k][pix][1] = (1.f - ly) * lx         * ((vy0 && vx1) ? 1.f : 0.f);
        s_w[k][pix][2] = ly * (1.f - lx)         * ((vy1 && vx0) ? 1.f : 0.f);
        s_w[k][pix][3] = ly * lx                 * ((vy1 && vx1) ? 1.f : 0.f);
    }
    __syncthreads();

    // ---- phase 1: build full val[32][1152] bf16 in LDS
    {
        int pix = t & 31, cg = t >> 5;        // cg: 0..7, owns 16 channels
        const float* xb = x + (size_t)b * CIN * HH * WW + (size_t)cg * 16 * HH * WW;
#pragma unroll 1
        for (int k = 0; k < 9; k++) {
            float4  w4 = *(const float4*)&s_w[k][pix][0];
            ushort4 o4 = *(const ushort4*)&s_o[k][pix][0];
            int oa = o4.x, ob = o4.y, oc = o4.z, od = o4.w;
            short* dst = &s_val[pix][k * 128 + cg * 16];
#pragma unroll
            for (int ci = 0; ci < 16; ci += 2) {
                const float* xc0 = xb + (size_t)ci * (HH * WW);
                const float* xc1 = xc0 + HH * WW;
                float v0 = w4.x * xc0[oa] + w4.y * xc0[ob] + w4.z * xc0[oc] + w4.w * xc0[od];
                float v1 = w4.x * xc1[oa] + w4.y * xc1[ob] + w4.z * xc1[oc] + w4.w * xc1[od];
                unsigned pk = (unsigned)(ushort)f2bf(v0) | ((unsigned)(ushort)f2bf(v1) << 16);
                *(unsigned*)(dst + ci) = pk;
            }
            xb -= (size_t)16 * HH * WW * 0;   // (xb fixed per cg; channel offset via ci)
        }
    }
    __syncthreads();

    // ---- phase 2: MFMA. wave handles 64 co x 32 pix (4 co-tiles x 2 pix-tiles)
    int wv = t >> 6;
    int l  = t & 63;
    int lane16 = l & 15, quad = l >> 4;

    f32x4 z = {0.f, 0.f, 0.f, 0.f};
    f32x4 acc[4][2];
#pragma unroll
    for (int i = 0; i < 4; i++)
#pragma unroll
        for (int j = 0; j < 2; j++) acc[i][j] = z;

    const short* wbase = wb + (size_t)(wv * 64 + lane16) * KK + quad * 8;

#pragma unroll 2
    for (int ks = 0; ks < 36; ks++) {
        int ck0 = ks * 32;
        bf16x8 a0 = *(const bf16x8*)(wbase + (size_t)0  * 16 * KK + ck0);
        bf16x8 a1 = *(const bf16x8*)(wbase + (size_t)1  * 16 * KK + ck0);
        bf16x8 a2 = *(const bf16x8*)(wbase + (size_t)2  * 16 * KK + ck0);
        bf16x8 a3 = *(const bf16x8*)(wbase + (size_t)3  * 16 * KK + ck0);
        bf16x8 b0 = *(const bf16x8*)&s_val[lane16     ][ck0 + quad * 8];
        bf16x8 b1 = *(const bf16x8*)&s_val[16 + lane16][ck0 + quad * 8];
        acc[0][0] = __builtin_amdgcn_mfma_f32_16x16x32_bf16(a0, b0, acc[0][0], 0, 0, 0);
        acc[1][0] = __builtin_amdgcn_mfma_f32_16x16x32_bf16(a1, b0, acc[1][0], 0, 0, 0);
        acc[2][0] = __builtin_amdgcn_mfma_f32_16x16x32_bf16(a2, b0, acc[2][0], 0, 0, 0);
        acc[3][0] = __builtin_amdgcn_mfma_f32_16x16x32_bf16(a3, b0, acc[3][0], 0, 0, 0);
        acc[0][1] = __builtin_amdgcn_mfma_f32_16x16x32_bf16(a0, b1, acc[0][1], 0, 0, 0);
        acc[1][1] = __builtin_amdgcn_mfma_f32_16x16x32_bf16(a1, b1, acc[1][1], 0, 0, 0);
        acc[2][1] = __builtin_amdgcn_mfma_f32_16x16x32_bf16(a2, b1, acc[2][1], 0, 0, 0);
        acc[3][1] = __builtin_amdgcn_mfma_f32_16x16x32_bf16(a3, b1, acc[3][1], 0, 0, 0);
    }

    // ---- epilogue: bias + relu + store. D: col(pix)=lane16, row(co)=quad*4+r
    const float* ob = out;  (void)ob;
#pragma unroll
    for (int ct = 0; ct < 4; ct++) {
        int co = wv * 64 + ct * 16 + quad * 4;
#pragma unroll
        for (int pt = 0; pt < 2; pt++) {
            int colx = w0 + pt * 16 + lane16;
#pragma unroll
            for (int r = 0; r < 4; r++) {
                float v = acc[ct][pt][r] + bias[co + r];
                out[(((size_t)b * COUT + co + r) * HH + h) * WW + colx] = fmaxf(v, 0.f);
            }
        }
    }
}

extern "C" void kernel_launch(void* const* d_in, const int* in_sizes, int n_in,
                              void* d_out, int out_size, void* d_ws, size_t ws_size,
                              hipStream_t stream) {
    const float* x     = (const float*)d_in[0];
    const float* w_off = (const float*)d_in[1];
    const float* b_off = (const float*)d_in[2];
    const float* w_def = (const float*)d_in[3];
    const float* b_def = (const float*)d_in[4];
    float* out = (float*)d_out;

    // ws: offset fp32 [8*18*4096], then wb bf16 [256*1152]
    float* offset = (float*)d_ws;
    short* wbb    = (short*)(offset + (size_t)8 * 18 * HH * WW);

    cast_w<<<COUT, 256, 0, stream>>>(w_def, wbb);
    init_off<<<(8 * 18 * HH * WW) / 256, 256, 0, stream>>>(b_off, offset);
    off_conv_part<<<dim3(16, 8, 4), 256, 0, stream>>>(x, w_off, offset);
    deform_mfma<<<8 * 64 * (WW / TP), 256, 0, stream>>>(x, offset, wbb, b_def, out);
}

// Round 3
// 251.577 us; speedup vs baseline: 2.4744x; 1.0767x over previous
//
#include <hip/hip_runtime.h>
#include <hip/hip_bf16.h>

#define HH 64
#define WW 64
#define CIN 128
#define COUT 256
#define KK 1152          // CIN*9
#define TP 32            // pixels per block tile
#define DSV 136          // deform s_val chunk row stride (128+8)
#define OSV 296          // off s_val chunk row stride (288+8)

typedef short bf16x8 __attribute__((ext_vector_type(8)));
typedef float f32x4  __attribute__((ext_vector_type(4)));

struct __attribute__((packed, aligned(4))) f2a { float x, y; };  // 4B-aligned float2

__device__ inline short f2bf(float f) {
    union { float f; unsigned u; } v; v.f = f;
    unsigned r = v.u + 0x7FFFu + ((v.u >> 16) & 1u);   // RNE
    return (short)(r >> 16);
}

// ---- kernel 0: deform weights -> bf16, k-major ck' = k*128+c
__global__ void cast_w(const float* __restrict__ wd, short* __restrict__ wb) {
    int co = blockIdx.x;                       // 0..255
    for (int ck = threadIdx.x; ck < KK; ck += 256) {
        int c = ck & 127, k = ck >> 7;
        wb[co * KK + ck] = f2bf(wd[co * KK + c * 9 + k]);
    }
}

// ---- kernel 1: offset-conv weights -> bf16 [32][1152], natural ck = c*9+k, rows 18..31 zero
__global__ void cast_woff(const float* __restrict__ w, short* __restrict__ wb) {
    int co = blockIdx.x;                       // 0..31
    for (int ck = threadIdx.x; ck < KK; ck += 256)
        wb[co * KK + ck] = (co < 18) ? f2bf(w[co * KK + ck]) : (short)0;
}

// ---- kernel 2: offset conv as bf16 MFMA im2col GEMM (M=18 pad 32)
// grid 1024: b=bi&7 (XCD pin), h=(bi>>3)&63, tile=bi>>9
__global__ __launch_bounds__(256, 4) void off_mfma(const float* __restrict__ x,
                                                   const short* __restrict__ wb,
                                                   const float* __restrict__ bo,
                                                   float* __restrict__ off) {
    __shared__ short s_val[2][TP][OSV];

    int t = threadIdx.x, bi = blockIdx.x;
    int b = bi & 7, h = (bi >> 3) & 63, tile = bi >> 9, w0 = tile * TP;
    int pix = t & 31, j = t >> 5;
    int wp = w0 + pix;
    const float* xb = x + ((size_t)b * CIN << 12);

    auto build = [&](int c0, int buf) {
#pragma unroll
        for (int ci = 0; ci < 4; ci++) {
            int cl = j * 4 + ci;
            const float* pl = xb + ((size_t)(c0 + cl) << 12);
            short* dst = &s_val[buf][pix][cl * 9];
#pragma unroll
            for (int k = 0; k < 9; k++) {
                int row = h + k / 3 - 1, col = wp + k % 3 - 1;
                float v = 0.f;
                if (row >= 0 && row < HH && col >= 0 && col < WW) v = pl[(row << 6) + col];
                dst[k] = f2bf(v);
            }
        }
    };

    int wv = t >> 6, l = t & 63, lane16 = l & 15, quad = l >> 4;
    int mt = wv >> 1, nt = wv & 1;
    f32x4 acc = {0.f, 0.f, 0.f, 0.f};

    build(0, 0);
    __syncthreads();
    for (int cc = 0; cc < 4; cc++) {
        if (cc < 3) build((cc + 1) * 32, (cc + 1) & 1);
        const short* A = wb + (size_t)(mt * 16 + lane16) * KK + cc * 288 + quad * 8;
        const short* B = &s_val[cc & 1][nt * 16 + lane16][quad * 8];
#pragma unroll
        for (int ks = 0; ks < 9; ks++) {
            bf16x8 a  = *(const bf16x8*)(A + ks * 32);
            bf16x8 bf = *(const bf16x8*)(B + ks * 32);
            acc = __builtin_amdgcn_mfma_f32_16x16x32_bf16(a, bf, acc, 0, 0, 0);
        }
        __syncthreads();
    }
    int cob = mt * 16 + quad * 4;
#pragma unroll
    for (int r = 0; r < 4; r++) {
        int co = cob + r;
        if (co < 18)
            off[(((size_t)b * 18 + co) << 12) + (h << 6) + w0 + nt * 16 + lane16] = acc[r] + bo[co];
    }
}

// ---- kernel 3: fused sampling + bf16 MFMA contraction + bias + relu
// grid 1024: b=bi&7, h=(bi>>3)&63, tile=bi>>9. K chunked by kernel-point (128/chunk), dbuf.
__global__ __launch_bounds__(256, 4) void deform_mfma(const float* __restrict__ x,
                                                      const float* __restrict__ off,
                                                      const short* __restrict__ wb,
                                                      const float* __restrict__ bias,
                                                      float* __restrict__ out) {
    __shared__ float  s_w[9][TP][4];     // float2-pair weights, clamp/validity folded
    __shared__ ushort s_o[9][TP][2];     // two row-base offsets (clamped-x base)
    __shared__ short  s_val[2][TP][DSV];

    int t = threadIdx.x, bi = blockIdx.x;
    int b = bi & 7, h = (bi >> 3) & 63, tile = bi >> 9, w0 = tile * TP;

    // ---- sampling params: 9 kernel points x 32 pixels
    for (int jj = t; jj < 9 * TP; jj += 256) {
        int k = jj >> 5, pix = jj & 31, wp = w0 + pix;
        float dy = off[(((size_t)b * 18 + 2 * k    ) << 12) + (h << 6) + wp];
        float dx = off[(((size_t)b * 18 + 2 * k + 1) << 12) + (h << 6) + wp];
        float py = (float)(h + k / 3 - 1) + dy;
        float px = (float)(wp + k % 3 - 1) + dx;
        float y0f = floorf(py), x0f = floorf(px);
        float ly = py - y0f, lx = px - x0f;
        int y0 = (int)y0f, x0 = (int)x0f;
        // fold x-clamp into pair weights: value = a0*f2.x + a1*f2.y, f2 at clamped base
        float a0, a1;
        if (x0 >= 0 && x0 <= 62)      { a0 = 1.f - lx; a1 = lx; }
        else if (x0 == -1)            { a0 = lx;       a1 = 0.f; }
        else if (x0 == 63)            { a0 = 0.f;      a1 = 1.f - lx; }
        else                          { a0 = 0.f;      a1 = 0.f; }
        int xb0 = min(max(x0, 0), 62);
        bool vy0 = (y0 >= 0) && (y0 < HH);
        bool vy1 = (y0 >= -1) && (y0 < HH - 1);
        int y0c = min(max(y0, 0), HH - 1);
        int y1c = min(max(y0 + 1, 0), HH - 1);
        float wy0 = (1.f - ly) * (vy0 ? 1.f : 0.f);
        float wy1 = ly * (vy1 ? 1.f : 0.f);
        s_o[k][pix][0] = (ushort)((y0c << 6) + xb0);
        s_o[k][pix][1] = (ushort)((y1c << 6) + xb0);
        s_w[k][pix][0] = wy0 * a0;
        s_w[k][pix][1] = wy0 * a1;
        s_w[k][pix][2] = wy1 * a0;
        s_w[k][pix][3] = wy1 * a1;
    }
    __syncthreads();

    int pix = t & 31, cg = t >> 5;       // cg 0..7 owns 16 channels
    const float* xpl = x + (((size_t)b * CIN + cg * 16) << 12);

    auto build = [&](int k, int buf) {
        float4 w4 = *(const float4*)&s_w[k][pix][0];
        int o0 = s_o[k][pix][0], o1 = s_o[k][pix][1];
        short* dst = &s_val[buf][pix][cg * 16];
#pragma unroll
        for (int ci = 0; ci < 16; ci += 2) {
            const float* p0 = xpl + ((size_t)ci << 12);
            const float* p1 = p0 + 4096;
            f2a r00 = *(const f2a*)(p0 + o0);
            f2a r01 = *(const f2a*)(p0 + o1);
            f2a r10 = *(const f2a*)(p1 + o0);
            f2a r11 = *(const f2a*)(p1 + o1);
            float v0 = w4.x * r00.x + w4.y * r00.y + w4.z * r01.x + w4.w * r01.y;
            float v1 = w4.x * r10.x + w4.y * r10.y + w4.z * r11.x + w4.w * r11.y;
            unsigned pk = (unsigned)(ushort)f2bf(v0) | ((unsigned)(ushort)f2bf(v1) << 16);
            *(unsigned*)(dst + ci) = pk;
        }
    };

    int wv = t >> 6, l = t & 63, lane16 = l & 15, quad = l >> 4;
    f32x4 z = {0.f, 0.f, 0.f, 0.f};
    f32x4 acc[4][2];
#pragma unroll
    for (int i = 0; i < 4; i++)
#pragma unroll
        for (int jj2 = 0; jj2 < 2; jj2++) acc[i][jj2] = z;

    const short* wbase = wb + (size_t)(wv * 64 + lane16) * KK + quad * 8;

    build(0, 0);
    __syncthreads();
    for (int k = 0; k < 9; k++) {
        if (k < 8) build(k + 1, (k + 1) & 1);
        const short* wk = wbase + k * 128;
#pragma unroll
        for (int ks = 0; ks < 4; ks++) {
            int ck0 = ks * 32;
            bf16x8 a0 = *(const bf16x8*)(wk + (size_t)0 * 16 * KK + ck0);
            bf16x8 a1 = *(const bf16x8*)(wk + (size_t)1 * 16 * KK + ck0);
            bf16x8 a2 = *(const bf16x8*)(wk + (size_t)2 * 16 * KK + ck0);
            bf16x8 a3 = *(const bf16x8*)(wk + (size_t)3 * 16 * KK + ck0);
            bf16x8 b0 = *(const bf16x8*)&s_val[k & 1][lane16     ][ck0 + quad * 8];
            bf16x8 b1 = *(const bf16x8*)&s_val[k & 1][16 + lane16][ck0 + quad * 8];
            acc[0][0] = __builtin_amdgcn_mfma_f32_16x16x32_bf16(a0, b0, acc[0][0], 0, 0, 0);
            acc[1][0] = __builtin_amdgcn_mfma_f32_16x16x32_bf16(a1, b0, acc[1][0], 0, 0, 0);
            acc[2][0] = __builtin_amdgcn_mfma_f32_16x16x32_bf16(a2, b0, acc[2][0], 0, 0, 0);
            acc[3][0] = __builtin_amdgcn_mfma_f32_16x16x32_bf16(a3, b0, acc[3][0], 0, 0, 0);
            acc[0][1] = __builtin_amdgcn_mfma_f32_16x16x32_bf16(a0, b1, acc[0][1], 0, 0, 0);
            acc[1][1] = __builtin_amdgcn_mfma_f32_16x16x32_bf16(a1, b1, acc[1][1], 0, 0, 0);
            acc[2][1] = __builtin_amdgcn_mfma_f32_16x16x32_bf16(a2, b1, acc[2][1], 0, 0, 0);
            acc[3][1] = __builtin_amdgcn_mfma_f32_16x16x32_bf16(a3, b1, acc[3][1], 0, 0, 0);
        }
        __syncthreads();
    }

    // ---- epilogue: bias + relu + store. D: col(pix)=lane16, row(co)=quad*4+r
    float bbv[4];
#pragma unroll
    for (int ct = 0; ct < 4; ct++) {
        int co = wv * 64 + ct * 16 + quad * 4;
#pragma unroll
        for (int pt = 0; pt < 2; pt++) {
            int colx = w0 + pt * 16 + lane16;
#pragma unroll
            for (int r = 0; r < 4; r++) {
                float v = acc[ct][pt][r] + bias[co + r];
                out[(((size_t)b * COUT + co + r) * HH + h) * WW + colx] = fmaxf(v, 0.f);
            }
        }
    }
    (void)bbv;
}

extern "C" void kernel_launch(void* const* d_in, const int* in_sizes, int n_in,
                              void* d_out, int out_size, void* d_ws, size_t ws_size,
                              hipStream_t stream) {
    const float* x     = (const float*)d_in[0];
    const float* w_off = (const float*)d_in[1];
    const float* b_off = (const float*)d_in[2];
    const float* w_def = (const float*)d_in[3];
    const float* b_def = (const float*)d_in[4];
    float* out = (float*)d_out;

    // ws: offset fp32 [8*18*4096], wb deform bf16 [256*1152], wboff bf16 [32*1152]
    float* offset = (float*)d_ws;
    short* wbb    = (short*)(offset + (size_t)8 * 18 * HH * WW);
    short* wboff  = wbb + (size_t)COUT * KK;

    cast_w<<<COUT, 256, 0, stream>>>(w_def, wbb);
    cast_woff<<<32, 256, 0, stream>>>(w_off, wboff);
    off_mfma<<<1024, 256, 0, stream>>>(x, wboff, b_off, offset);
    deform_mfma<<<1024, 256, 0, stream>>>(x, offset, wbb, b_def, out);
}

// Round 4
// 147.683 us; speedup vs baseline: 4.2151x; 1.7035x over previous
//
#include <hip/hip_runtime.h>
#include <hip/hip_bf16.h>

#define HH 64
#define WW 64
#define CIN 128
#define COUT 256
#define KK 1152          // CIN*9
#define TP 32            // pixels per block tile
#define PW 66            // padded NHWC width/height
#define XTIMG (PW*PW*CIN)  // elems per padded image = 557568

typedef short bf16x8 __attribute__((ext_vector_type(8)));
typedef float f32x4  __attribute__((ext_vector_type(4)));

__device__ inline short f2bf(float f) {
    union { float f; unsigned u; } v; v.f = f;
    unsigned r = v.u + 0x7FFFu + ((v.u >> 16) & 1u);   // RNE
    return (short)(r >> 16);
}
__device__ inline float bf2f(ushort u) {
    union { unsigned u; float f; } v; v.u = (unsigned)u << 16; return v.f;
}

// ---- kernel 0: x [8][128][64][64] f32 -> xt [8][66][66][128] bf16, zero borders
__global__ __launch_bounds__(256) void transpose_x(const float* __restrict__ x,
                                                   ushort* __restrict__ xt) {
    __shared__ short tl[64][130];
    int hp = blockIdx.x;             // 0..65
    int b  = blockIdx.y;
    int t  = threadIdx.x;
    ushort* row = xt + ((size_t)b * PW + hp) * PW * CIN;
    if (hp == 0 || hp == PW - 1) {
        for (int i = 0; i < 33; i++) row[i * 256 + t] = 0;
        return;
    }
    int h = hp - 1;
    int w = t & 63, cq = t >> 6;
    for (int it = 0; it < 32; it++) {
        int c = it * 4 + cq;
        tl[w][c] = f2bf(x[(((size_t)b * CIN + c) << 12) + (h << 6) + w]);
    }
    __syncthreads();
    for (int it = 0; it < 33; it++) {
        int flat = it * 256 + t;     // 0..8447
        int wp = flat >> 7, c = flat & 127;
        ushort v = (wp == 0 || wp == PW - 1) ? (ushort)0 : (ushort)tl[wp - 1][c];
        row[flat] = v;
    }
}

// ---- kernel 1: deform weights -> MFMA A-fragment order
// wf[((m*36+ks)*64 + l)*8 + j] = bf16(w_def[m*16+(l&15)][c*9+k]), ck'=ks*32+(l>>4)*8+j, c=ck'&127, k=ck'>>7
__global__ void cast_wf(const float* __restrict__ wd, short* __restrict__ wf) {
    int ks = blockIdx.x, m = blockIdx.y, l = threadIdx.x;
    int co = m * 16 + (l & 15);
    bf16x8 v;
#pragma unroll
    for (int j = 0; j < 8; j++) {
        int ckp = ks * 32 + ((l >> 4) << 3) + j;
        int c = ckp & 127, k = ckp >> 7;
        v[j] = f2bf(wd[(size_t)co * KK + c * 9 + k]);
    }
    *(bf16x8*)(wf + ((size_t)(m * 36 + ks) * 64 + l) * 8) = v;
}

// ---- kernel 2: offset weights -> fragment order, rows 18..31 zero
__global__ void cast_wfo(const float* __restrict__ w, short* __restrict__ wfo) {
    int ks = blockIdx.x, m = blockIdx.y, l = threadIdx.x;
    int co = m * 16 + (l & 15);
    bf16x8 v;
#pragma unroll
    for (int j = 0; j < 8; j++) {
        int ckp = ks * 32 + ((l >> 4) << 3) + j;
        int c = ckp & 127, k = ckp >> 7;
        v[j] = (co < 18) ? f2bf(w[(size_t)co * KK + c * 9 + k]) : (short)0;
    }
    *(bf16x8*)(wfo + ((size_t)(m * 36 + ks) * 64 + l) * 8) = v;
}

// ---- kernel 3: offset conv as MFMA GEMM over NHWC-bf16 (M=18 pad 32)
__global__ __launch_bounds__(256, 4) void off_mfma(const ushort* __restrict__ xt,
                                                   const short* __restrict__ wfo,
                                                   const float* __restrict__ bo,
                                                   float* __restrict__ off) {
    __shared__ short s_val[2][TP][128];

    int t = threadIdx.x, bi = blockIdx.x;
    int b = bi & 7, h = (bi >> 3) & 63, tile = bi >> 9, w0 = tile * TP;
    const ushort* xb = xt + (size_t)b * XTIMG;

    bf16x8 r0, r1;
    int cpix = t >> 3;
    int g0 = ((2 * t) & 15), g1 = g0 + 1;
    int gs0 = (g0 ^ (cpix & 15)) * 8, gs1 = (g1 ^ (cpix & 15)) * 8;

    auto oload = [&](int k) {
        const ushort* base = xb + ((size_t)(h + k / 3) * PW + w0 + k % 3) * CIN;
        r0 = *(const bf16x8*)(base + t * 16);
        r1 = *(const bf16x8*)(base + t * 16 + 8);
    };
    auto ostore = [&](int buf) {
        *(bf16x8*)&s_val[buf][cpix][gs0] = r0;
        *(bf16x8*)&s_val[buf][cpix][gs1] = r1;
    };

    int wv = t >> 6, l = t & 63, lane16 = l & 15, quad = l >> 4;
    int mt = wv >> 1, nt = wv & 1;
    f32x4 acc = {0.f, 0.f, 0.f, 0.f};
    const short* Ab = wfo + (size_t)l * 8 + (size_t)mt * 36 * 512;

    oload(0); ostore(0);
    __syncthreads();
    for (int k = 0; k < 9; k++) {
        if (k < 8) oload(k + 1);
#pragma unroll
        for (int ksp = 0; ksp < 4; ksp++) {
            int ks = k * 4 + ksp;
            bf16x8 a  = *(const bf16x8*)(Ab + ks * 512);
            bf16x8 bf = *(const bf16x8*)&s_val[k & 1][nt * 16 + lane16][((ksp * 4 + quad) ^ lane16) * 8];
            acc = __builtin_amdgcn_mfma_f32_16x16x32_bf16(a, bf, acc, 0, 0, 0);
        }
        if (k < 8) ostore((k + 1) & 1);
        __syncthreads();
    }
    int cob = mt * 16 + quad * 4;
#pragma unroll
    for (int r = 0; r < 4; r++) {
        int co = cob + r;
        if (co < 18)
            off[(((size_t)b * 18 + co) << 12) + (h << 6) + w0 + nt * 16 + lane16] = acc[r] + bo[co];
    }
}

// ---- kernel 4: fused sampling (NHWC gather) + MFMA + bias + relu
__global__ __launch_bounds__(256, 4) void deform_mfma(const ushort* __restrict__ xt,
                                                      const float* __restrict__ off,
                                                      const short* __restrict__ wf,
                                                      const float* __restrict__ bias,
                                                      float* __restrict__ out) {
    __shared__ float4  s_w[9][TP];    // (w00,w01,w10,w11), clamp/validity folded
    __shared__ ushort2 s_o[9][TP];    // two row-base padded locations
    __shared__ short   s_val[2][TP][128];

    int t = threadIdx.x, bi = blockIdx.x;
    int b = bi & 7, h = (bi >> 3) & 63, tile = bi >> 9, w0 = tile * TP;

    for (int jj = t; jj < 9 * TP; jj += 256) {
        int k = jj >> 5, pixj = jj & 31, wp = w0 + pixj;
        float dy = off[(((size_t)b * 18 + 2 * k    ) << 12) + (h << 6) + wp];
        float dx = off[(((size_t)b * 18 + 2 * k + 1) << 12) + (h << 6) + wp];
        float py = (float)(h + k / 3 - 1) + dy;
        float px = (float)(wp + k % 3 - 1) + dx;
        float y0f = floorf(py), x0f = floorf(px);
        float ly = py - y0f, lx = px - x0f;
        int y0 = (int)y0f, x0 = (int)x0f;
        float a0, a1;
        if (x0 >= 0 && x0 <= 62)      { a0 = 1.f - lx; a1 = lx; }
        else if (x0 == -1)            { a0 = lx;       a1 = 0.f; }
        else if (x0 == 63)            { a0 = 0.f;      a1 = 1.f - lx; }
        else                          { a0 = 0.f;      a1 = 0.f; }
        int xb0 = min(max(x0, 0), 62);
        bool vy0 = (y0 >= 0) && (y0 < HH);
        bool vy1 = (y0 >= -1) && (y0 < HH - 1);
        int y0c = min(max(y0, 0), HH - 1);
        int y1c = min(max(y0 + 1, 0), HH - 1);
        float wy0 = (1.f - ly) * (vy0 ? 1.f : 0.f);
        float wy1 = ly * (vy1 ? 1.f : 0.f);
        s_o[k][pixj] = make_ushort2((ushort)((y0c + 1) * PW + xb0 + 1),
                                    (ushort)((y1c + 1) * PW + xb0 + 1));
        s_w[k][pixj] = make_float4(wy0 * a0, wy0 * a1, wy1 * a0, wy1 * a1);
    }
    __syncthreads();

    int pix = t & 31, cs = t >> 5, pm = pix & 15;
    const ushort* xb = xt + (size_t)b * XTIMG;
    int gs0 = ((cs * 2) ^ pm) * 8, gs1 = ((cs * 2 + 1) ^ pm) * 8;

    bf16x8 r[8];
    auto gload = [&](int k) {
        ushort2 o = s_o[k][pix];
        const ushort* p0 = xb + (size_t)o.x * CIN + cs * 16;
        const ushort* p1 = xb + (size_t)o.y * CIN + cs * 16;
        r[0] = *(const bf16x8*)(p0);       r[1] = *(const bf16x8*)(p0 + 8);
        r[2] = *(const bf16x8*)(p0 + 128); r[3] = *(const bf16x8*)(p0 + 136);
        r[4] = *(const bf16x8*)(p1);       r[5] = *(const bf16x8*)(p1 + 8);
        r[6] = *(const bf16x8*)(p1 + 128); r[7] = *(const bf16x8*)(p1 + 136);
    };
    auto gstore = [&](int k, int buf) {
        float4 w4 = s_w[k][pix];
        bf16x8 va, vb;
#pragma unroll
        for (int j = 0; j < 8; j++) {
            float v = w4.x * bf2f((ushort)r[0][j]) + w4.y * bf2f((ushort)r[2][j])
                    + w4.z * bf2f((ushort)r[4][j]) + w4.w * bf2f((ushort)r[6][j]);
            float u = w4.x * bf2f((ushort)r[1][j]) + w4.y * bf2f((ushort)r[3][j])
                    + w4.z * bf2f((ushort)r[5][j]) + w4.w * bf2f((ushort)r[7][j]);
            va[j] = f2bf(v);
            vb[j] = f2bf(u);
        }
        *(bf16x8*)&s_val[buf][pix][gs0] = va;
        *(bf16x8*)&s_val[buf][pix][gs1] = vb;
    };

    int wv = t >> 6, l = t & 63, lane16 = l & 15, quad = l >> 4;
    f32x4 z = {0.f, 0.f, 0.f, 0.f};
    f32x4 acc[4][2];
#pragma unroll
    for (int i = 0; i < 4; i++)
#pragma unroll
        for (int j = 0; j < 2; j++) acc[i][j] = z;

    const short* Ab = wf + (size_t)l * 8 + (size_t)(wv * 4) * 36 * 512;

    gload(0); gstore(0, 0);
    __syncthreads();
    for (int k = 0; k < 9; k++) {
        if (k < 8) gload(k + 1);
#pragma unroll
        for (int ksp = 0; ksp < 4; ksp++) {
            int ks = k * 4 + ksp;
            bf16x8 a0 = *(const bf16x8*)(Ab + (0 * 36 + ks) * 512);
            bf16x8 a1 = *(const bf16x8*)(Ab + (1 * 36 + ks) * 512);
            bf16x8 a2 = *(const bf16x8*)(Ab + (2 * 36 + ks) * 512);
            bf16x8 a3 = *(const bf16x8*)(Ab + (3 * 36 + ks) * 512);
            int gsw = ((ksp * 4 + quad) ^ lane16) * 8;
            bf16x8 b0 = *(const bf16x8*)&s_val[k & 1][lane16     ][gsw];
            bf16x8 b1 = *(const bf16x8*)&s_val[k & 1][16 + lane16][gsw];
            acc[0][0] = __builtin_amdgcn_mfma_f32_16x16x32_bf16(a0, b0, acc[0][0], 0, 0, 0);
            acc[1][0] = __builtin_amdgcn_mfma_f32_16x16x32_bf16(a1, b0, acc[1][0], 0, 0, 0);
            acc[2][0] = __builtin_amdgcn_mfma_f32_16x16x32_bf16(a2, b0, acc[2][0], 0, 0, 0);
            acc[3][0] = __builtin_amdgcn_mfma_f32_16x16x32_bf16(a3, b0, acc[3][0], 0, 0, 0);
            acc[0][1] = __builtin_amdgcn_mfma_f32_16x16x32_bf16(a0, b1, acc[0][1], 0, 0, 0);
            acc[1][1] = __builtin_amdgcn_mfma_f32_16x16x32_bf16(a1, b1, acc[1][1], 0, 0, 0);
            acc[2][1] = __builtin_amdgcn_mfma_f32_16x16x32_bf16(a2, b1, acc[2][1], 0, 0, 0);
            acc[3][1] = __builtin_amdgcn_mfma_f32_16x16x32_bf16(a3, b1, acc[3][1], 0, 0, 0);
        }
        if (k < 8) gstore(k + 1, (k + 1) & 1);
        __syncthreads();
    }

#pragma unroll
    for (int ct = 0; ct < 4; ct++) {
        int co = wv * 64 + ct * 16 + quad * 4;
#pragma unroll
        for (int pt = 0; pt < 2; pt++) {
            int colx = w0 + pt * 16 + lane16;
#pragma unroll
            for (int rr = 0; rr < 4; rr++) {
                float v = acc[ct][pt][rr] + bias[co + rr];
                out[(((size_t)b * COUT + co + rr) << 12) + (h << 6) + colx] = fmaxf(v, 0.f);
            }
        }
    }
}

extern "C" void kernel_launch(void* const* d_in, const int* in_sizes, int n_in,
                              void* d_out, int out_size, void* d_ws, size_t ws_size,
                              hipStream_t stream) {
    const float* x     = (const float*)d_in[0];
    const float* w_off = (const float*)d_in[1];
    const float* b_off = (const float*)d_in[2];
    const float* w_def = (const float*)d_in[3];
    const float* b_def = (const float*)d_in[4];
    float* out = (float*)d_out;

    // ws: offset f32 [8*18*4096] | wf bf16 [16*36*512] | wfo bf16 [2*36*512] | xt bf16 [8*66*66*128]
    float*  offset = (float*)d_ws;
    short*  wf     = (short*)(offset + (size_t)8 * 18 * HH * WW);
    short*  wfo    = wf + (size_t)16 * 36 * 512;
    ushort* xt     = (ushort*)(wfo + (size_t)2 * 36 * 512);

    transpose_x<<<dim3(PW, 8), 256, 0, stream>>>(x, xt);
    cast_wf<<<dim3(36, 16), 64, 0, stream>>>(w_def, wf);
    cast_wfo<<<dim3(36, 2), 64, 0, stream>>>(w_off, wfo);
    off_mfma<<<1024, 256, 0, stream>>>(xt, wfo, b_off, offset);
    deform_mfma<<<1024, 256, 0, stream>>>(xt, offset, wf, b_def, out);
}

// Round 5
// 135.337 us; speedup vs baseline: 4.5996x; 1.0912x over previous
//
#include <hip/hip_runtime.h>
#include <hip/hip_bf16.h>

#define HH 64
#define WW 64
#define CIN 128
#define COUT 256
#define KK 1152            // CIN*9
#define TP 32              // pixels per block tile
#define PW 66              // padded NHWC width/height
#define XTIMG (PW*PW*CIN)  // elems per padded image = 557568
#define RS 264             // s_raw region stride in shorts (512B data + 16B pad, odd 16B-granule)

typedef short bf16x8 __attribute__((ext_vector_type(8)));
typedef float f32x4  __attribute__((ext_vector_type(4)));

__device__ inline short f2bf(float f) {
    union { float f; unsigned u; } v; v.f = f;
    unsigned r = v.u + 0x7FFFu + ((v.u >> 16) & 1u);   // RNE
    return (short)(r >> 16);
}
__device__ inline float bf2f(ushort u) {
    union { unsigned u; float f; } v; v.u = (unsigned)u << 16; return v.f;
}

// ---- kernel 0: x [8][128][64][64] f32 -> xt [8][66][66][128] bf16, zero borders
__global__ __launch_bounds__(256) void transpose_x(const float* __restrict__ x,
                                                   ushort* __restrict__ xt) {
    int hp = blockIdx.x;             // 0..65
    int b  = blockIdx.y;
    int t  = threadIdx.x;
    ushort* row = xt + ((size_t)b * PW + hp) * PW * CIN;   // 8448 elems
    if (hp == 0 || hp == PW - 1) {
        ushort4 z4 = {0, 0, 0, 0};
        for (int f = t; f < 2112; f += 256) ((ushort4*)row)[f] = z4;
        return;
    }
    __shared__ short tl[66 * 132];   // [wp][c], stride 132
    int h = hp - 1;
    if (t < 128) { tl[t] = 0; tl[65 * 132 + t] = 0; }
    const float* xbh = x + (((size_t)b * CIN) << 12) + (h << 6);
#pragma unroll
    for (int it = 0; it < 8; it++) {
        int c  = it * 16 + (t >> 4);
        int w4 = (t & 15) * 4;
        float4 v = *(const float4*)(xbh + ((size_t)c << 12) + w4);
        tl[(w4 + 1) * 132 + c] = f2bf(v.x);
        tl[(w4 + 2) * 132 + c] = f2bf(v.y);
        tl[(w4 + 3) * 132 + c] = f2bf(v.z);
        tl[(w4 + 4) * 132 + c] = f2bf(v.w);
    }
    __syncthreads();
    for (int f = t; f < 2112; f += 256) {      // 2112 ushort4 = 8448 elems
        int wp = f >> 5, c4 = (f & 31) * 4;
        const short* s = &tl[wp * 132 + c4];
        ushort4 v; v.x = s[0]; v.y = s[1]; v.z = s[2]; v.w = s[3];
        ((ushort4*)row)[f] = v;
    }
}

// ---- kernel 1: both weight tensors -> MFMA A-fragment order (bf16)
// m<16: deform tile m; m>=16: offset tile m-16 (rows 18..31 zeroed)
__global__ void cast_wall(const float* __restrict__ wd, const float* __restrict__ wo,
                          short* __restrict__ wf, short* __restrict__ wfo) {
    int ks = blockIdx.x, m = blockIdx.y, l = threadIdx.x;
    bf16x8 v;
    if (m < 16) {
        int co = m * 16 + (l & 15);
#pragma unroll
        for (int j = 0; j < 8; j++) {
            int ckp = ks * 32 + ((l >> 4) << 3) + j;
            int c = ckp & 127, k = ckp >> 7;
            v[j] = f2bf(wd[(size_t)co * KK + c * 9 + k]);
        }
        *(bf16x8*)(wf + ((size_t)(m * 36 + ks) * 64 + l) * 8) = v;
    } else {
        int mm = m - 16;
        int co = mm * 16 + (l & 15);
#pragma unroll
        for (int j = 0; j < 8; j++) {
            int ckp = ks * 32 + ((l >> 4) << 3) + j;
            int c = ckp & 127, k = ckp >> 7;
            v[j] = (co < 18) ? f2bf(wo[(size_t)co * KK + c * 9 + k]) : (short)0;
        }
        *(bf16x8*)(wfo + ((size_t)(mm * 36 + ks) * 64 + l) * 8) = v;
    }
}

// ---- kernel 2: FUSED offset-conv MFMA + sampling + deform MFMA + bias + relu
// grid 1024: b=bi&7 (XCD pin), h=(bi>>3)&63, tile=bi>>9
__global__ __launch_bounds__(256, 3) void fused_deform(const ushort* __restrict__ xt,
                                                       const short* __restrict__ wf,
                                                       const short* __restrict__ wfo,
                                                       const float* __restrict__ bo,
                                                       const float* __restrict__ bias,
                                                       float* __restrict__ out) {
    __shared__ short   s_raw[64 * RS];   // 33792 B: phase0 dbuf (2x8KB) then gather raw buffer
    __shared__ short   s_val[TP][128];   // 8192 B: B-fragments (xor-swizzled)
    __shared__ float   s_off[18][TP];    // offsets from phase 0
    __shared__ float4  s_w[9][TP];       // bilinear weights, clamp/validity folded
    __shared__ ushort2 s_o[9][TP];       // two row-base padded locations

    int t = threadIdx.x, bi = blockIdx.x;
    int b = bi & 7, h = (bi >> 3) & 63, tile = bi >> 9, w0 = tile * TP;
    const ushort* xb = xt + (size_t)b * XTIMG;
    int wv = t >> 6, l = t & 63, lane16 = l & 15, quad = l >> 4;

    // ================= phase 0: offset conv (M=18 pad 32, K=1152) =================
    {
        short* sv0 = s_raw;
        short* sv1 = s_raw + 4096;
        int cpix = t >> 3;
        int g0 = 2 * (t & 7), g1 = g0 + 1;
        int gs0 = (g0 ^ (cpix & 15)) * 8, gs1 = (g1 ^ (cpix & 15)) * 8;
        bf16x8 r0, r1;
        auto oload = [&](int k) {
            const ushort* base = xb + ((size_t)(h + k / 3) * PW + w0 + k % 3) * CIN;
            r0 = *(const bf16x8*)(base + t * 16);
            r1 = *(const bf16x8*)(base + t * 16 + 8);
        };
        auto ostore = [&](int buf) {
            short* sv = buf ? sv1 : sv0;
            *(bf16x8*)(sv + cpix * 128 + gs0) = r0;
            *(bf16x8*)(sv + cpix * 128 + gs1) = r1;
        };
        int mt = wv >> 1, nt = wv & 1;
        f32x4 aoff = {0.f, 0.f, 0.f, 0.f};
        const short* Ab = wfo + (size_t)l * 8 + (size_t)mt * 36 * 512;

        oload(0); ostore(0);
        __syncthreads();
        for (int k = 0; k < 9; k++) {
            if (k < 8) oload(k + 1);
            const short* sv = (k & 1) ? sv1 : sv0;
#pragma unroll
            for (int ksp = 0; ksp < 4; ksp++) {
                bf16x8 a  = *(const bf16x8*)(Ab + (k * 4 + ksp) * 512);
                bf16x8 bf = *(const bf16x8*)(sv + (nt * 16 + lane16) * 128 + ((ksp * 4 + quad) ^ lane16) * 8);
                aoff = __builtin_amdgcn_mfma_f32_16x16x32_bf16(a, bf, aoff, 0, 0, 0);
            }
            if (k < 8) ostore((k + 1) & 1);
            __syncthreads();
        }
        int cob = mt * 16 + quad * 4;
#pragma unroll
        for (int r = 0; r < 4; r++) {
            int co = cob + r;
            if (co < 18) s_off[co][nt * 16 + lane16] = aoff[r] + bo[co];
        }
    }
    __syncthreads();

    // ================= sampling params: 9 kernel points x 32 pixels =================
    for (int jj = t; jj < 9 * TP; jj += 256) {
        int k = jj >> 5, pixj = jj & 31, wp = w0 + pixj;
        float dy = s_off[2 * k][pixj];
        float dx = s_off[2 * k + 1][pixj];
        float py = (float)(h + k / 3 - 1) + dy;
        float px = (float)(wp + k % 3 - 1) + dx;
        float y0f = floorf(py), x0f = floorf(px);
        float ly = py - y0f, lx = px - x0f;
        int y0 = (int)y0f, x0 = (int)x0f;
        float a0, a1;
        if (x0 >= 0 && x0 <= 62)      { a0 = 1.f - lx; a1 = lx; }
        else if (x0 == -1)            { a0 = lx;       a1 = 0.f; }
        else if (x0 == 63)            { a0 = 0.f;      a1 = 1.f - lx; }
        else                          { a0 = 0.f;      a1 = 0.f; }
        int xb0 = min(max(x0, 0), 62);
        bool vy0 = (y0 >= 0) && (y0 < HH);
        bool vy1 = (y0 >= -1) && (y0 < HH - 1);
        int y0c = min(max(y0, 0), HH - 1);
        int y1c = min(max(y0 + 1, 0), HH - 1);
        float wy0 = (1.f - ly) * (vy0 ? 1.f : 0.f);
        float wy1 = ly * (vy1 ? 1.f : 0.f);
        s_o[k][pixj] = make_ushort2((ushort)((y0c + 1) * PW + xb0 + 1),
                                    (ushort)((y1c + 1) * PW + xb0 + 1));
        s_w[k][pixj] = make_float4(wy0 * a0, wy0 * a1, wy1 * a0, wy1 * a1);
    }
    __syncthreads();

    // ================= phase 1: deform gather + MFMA =================
    // region g = pix + 32*r (512 B = 2 pixel-cols x 128 ch); 4 lanes/region, 64 B each instr
    int g = t >> 2, sub = t & 3;
    int gpix = g & 31, gr = g >> 5;
    bf16x8 rv[8];
    auto gload = [&](int k) {
        ushort2 o = s_o[k][gpix];
        int loc = gr ? o.y : o.x;
        const ushort* p = xb + (size_t)loc * CIN + sub * 8;
#pragma unroll
        for (int i = 0; i < 8; i++) rv[i] = *(const bf16x8*)(p + i * 32);
    };
    auto gstore = [&]() {
        short* d = s_raw + g * RS + sub * 8;
#pragma unroll
        for (int i = 0; i < 8; i++) *(bf16x8*)(d + i * 32) = rv[i];
    };
    int cpix2 = t & 31, cg = t >> 5;
    auto combine = [&](int k) {
        float4 w4 = s_w[k][cpix2];
        const short* r0b = s_raw + cpix2 * RS;
        const short* r1b = s_raw + (cpix2 + 32) * RS;
#pragma unroll
        for (int j2 = 0; j2 < 2; j2++) {
            int ch = cg * 16 + j2 * 8;
            bf16x8 c00 = *(const bf16x8*)(r0b + ch);
            bf16x8 c01 = *(const bf16x8*)(r0b + 128 + ch);
            bf16x8 c10 = *(const bf16x8*)(r1b + ch);
            bf16x8 c11 = *(const bf16x8*)(r1b + 128 + ch);
            bf16x8 fr;
#pragma unroll
            for (int i = 0; i < 8; i++) {
                float v = w4.x * bf2f((ushort)c00[i]) + w4.y * bf2f((ushort)c01[i])
                        + w4.z * bf2f((ushort)c10[i]) + w4.w * bf2f((ushort)c11[i]);
                fr[i] = f2bf(v);
            }
            *(bf16x8*)&s_val[cpix2][((cg * 2 + j2) ^ (cpix2 & 15)) * 8] = fr;
        }
    };

    f32x4 z = {0.f, 0.f, 0.f, 0.f};
    f32x4 acc[4][2];
#pragma unroll
    for (int i = 0; i < 4; i++)
#pragma unroll
        for (int j = 0; j < 2; j++) acc[i][j] = z;
    const short* Aw = wf + (size_t)l * 8;

    gload(0);
    gstore();
    __syncthreads();
    combine(0);
    gload(1);
    __syncthreads();

    for (int k = 0; k < 9; k++) {
#pragma unroll
        for (int ksp = 0; ksp < 4; ksp++) {
            int ks = k * 4 + ksp;
            int gsw = ((ksp * 4 + quad) ^ lane16) * 8;
            bf16x8 b0 = *(const bf16x8*)&s_val[lane16     ][gsw];
            bf16x8 b1 = *(const bf16x8*)&s_val[16 + lane16][gsw];
            bf16x8 a0 = *(const bf16x8*)(Aw + (size_t)((wv * 4 + 0) * 36 + ks) * 512);
            bf16x8 a1 = *(const bf16x8*)(Aw + (size_t)((wv * 4 + 1) * 36 + ks) * 512);
            bf16x8 a2 = *(const bf16x8*)(Aw + (size_t)((wv * 4 + 2) * 36 + ks) * 512);
            bf16x8 a3 = *(const bf16x8*)(Aw + (size_t)((wv * 4 + 3) * 36 + ks) * 512);
            acc[0][0] = __builtin_amdgcn_mfma_f32_16x16x32_bf16(a0, b0, acc[0][0], 0, 0, 0);
            acc[1][0] = __builtin_amdgcn_mfma_f32_16x16x32_bf16(a1, b0, acc[1][0], 0, 0, 0);
            acc[2][0] = __builtin_amdgcn_mfma_f32_16x16x32_bf16(a2, b0, acc[2][0], 0, 0, 0);
            acc[3][0] = __builtin_amdgcn_mfma_f32_16x16x32_bf16(a3, b0, acc[3][0], 0, 0, 0);
            acc[0][1] = __builtin_amdgcn_mfma_f32_16x16x32_bf16(a0, b1, acc[0][1], 0, 0, 0);
            acc[1][1] = __builtin_amdgcn_mfma_f32_16x16x32_bf16(a1, b1, acc[1][1], 0, 0, 0);
            acc[2][1] = __builtin_amdgcn_mfma_f32_16x16x32_bf16(a2, b1, acc[2][1], 0, 0, 0);
            acc[3][1] = __builtin_amdgcn_mfma_f32_16x16x32_bf16(a3, b1, acc[3][1], 0, 0, 0);
        }
        if (k < 8) {
            gstore();                 // rv holds chunk k+1
            __syncthreads();          // s_raw(k+1) ready; all waves past MFMA(k)
            combine(k + 1);           // s_raw -> s_val
            if (k < 7) gload(k + 2);  // prefetch
            __syncthreads();          // s_val(k+1) ready
        }
    }

    // ---- epilogue: bias + relu + store. D: col(pix)=lane16, row(co)=quad*4+r
#pragma unroll
    for (int ct = 0; ct < 4; ct++) {
        int co = wv * 64 + ct * 16 + quad * 4;
#pragma unroll
        for (int pt = 0; pt < 2; pt++) {
            int colx = w0 + pt * 16 + lane16;
#pragma unroll
            for (int rr = 0; rr < 4; rr++) {
                float v = acc[ct][pt][rr] + bias[co + rr];
                out[(((size_t)b * COUT + co + rr) << 12) + (h << 6) + colx] = fmaxf(v, 0.f);
            }
        }
    }
}

extern "C" void kernel_launch(void* const* d_in, const int* in_sizes, int n_in,
                              void* d_out, int out_size, void* d_ws, size_t ws_size,
                              hipStream_t stream) {
    const float* x     = (const float*)d_in[0];
    const float* w_off = (const float*)d_in[1];
    const float* b_off = (const float*)d_in[2];
    const float* w_def = (const float*)d_in[3];
    const float* b_def = (const float*)d_in[4];
    float* out = (float*)d_out;

    // ws: wf bf16 [16*36*512] | wfo bf16 [2*36*512] | xt bf16 [8*66*66*128]
    short*  wf  = (short*)d_ws;
    short*  wfo = wf + (size_t)16 * 36 * 512;
    ushort* xt  = (ushort*)(wfo + (size_t)2 * 36 * 512);

    transpose_x<<<dim3(PW, 8), 256, 0, stream>>>(x, xt);
    cast_wall<<<dim3(36, 18), 64, 0, stream>>>(w_def, w_off, wf, wfo);
    fused_deform<<<1024, 256, 0, stream>>>(xt, wf, wfo, b_off, b_def, out);
}